// Round 1
// baseline (6501.871 us; speedup 1.0000x reference)
//
#include <hip/hip_runtime.h>
#include <math.h>

// Shapes
#define Bb 16
#define Tt 288
#define Tc 289          // conv output length: 288 + 6 + 6 - 12 + 1
#define Nn 1024
#define Dd 32
#define Mm 4096
#define Kk 8
#define Hh 4
#define HD 8
#define OD 32768        // N*D
#define NEGV (-10000.0f)

__device__ __forceinline__ float gelu_exact(float x) {
    return 0.5f * x * (1.0f + erff(x * 0.7071067811865476f));
}

// ---------------------------------------------------------------------------
// Stage 1: depthwise conv (k=12, pad 6/6) + bias + GELU.
// x: [B][T][N] -> Y: [(b*289+t)][n]   (column-major for the GEMM: K=n contiguous)
// ---------------------------------------------------------------------------
__global__ __launch_bounds__(256) void dwconv_kernel(
    const float* __restrict__ x, const float* __restrict__ w,
    const float* __restrict__ bias, float* __restrict__ Y)
{
    int tid = blockIdx.x * 256 + threadIdx.x;
    if (tid >= Bb * Tc * Nn) return;
    int n  = tid & (Nn - 1);
    int bt = tid >> 10;
    int b  = bt / Tc;
    int t  = bt - b * Tc;
    const float* xp = x + (size_t)b * Tt * Nn + n;
    const float* wp = w + n * 12;
    float acc = 0.f;
#pragma unroll
    for (int k = 0; k < 12; k++) {
        int ti = t - 6 + k;
        if (ti >= 0 && ti < Tt) acc += xp[(size_t)ti * Nn] * wp[k];
    }
    acc += bias[n];
    Y[(size_t)bt * Nn + n] = gelu_exact(acc);
}

// ---------------------------------------------------------------------------
// Stage 2: Z[o][b,t] = sum_c W[o][c] * Y[b,t][c];  qmean[b][o] = mean_t gelu(Z + pwb[o])
// Block: fixed b, 64-o tile, loops all 289 t in chunks of 64 -> no atomics.
// 16x16 threads, 4x4 register tile, K-tile 16 staged in LDS.
// ---------------------------------------------------------------------------
__global__ __launch_bounds__(256) void encode_gemm(
    const float* __restrict__ Y, const float* __restrict__ W,
    const float* __restrict__ pwb, float* __restrict__ qmean)
{
    int b  = blockIdx.y;
    int o0 = blockIdx.x * 64;
    int tid = threadIdx.x;
    int ty = tid >> 4, tx = tid & 15;
    int lr = tid >> 2;          // 0..63
    int lc = (tid & 3) * 4;     // 0,4,8,12

    __shared__ float Ws[16][64];
    __shared__ float Ys[16][64];
    __shared__ float red[64][16];

    float tsum[4] = {0.f, 0.f, 0.f, 0.f};

    for (int t0 = 0; t0 < Tc; t0 += 64) {
        float acc[4][4];
#pragma unroll
        for (int i = 0; i < 4; i++)
#pragma unroll
            for (int j = 0; j < 4; j++) acc[i][j] = 0.f;

        for (int k0 = 0; k0 < Nn; k0 += 16) {
            float4 wv = *(const float4*)(W + (size_t)(o0 + lr) * Nn + k0 + lc);
            float4 yv = make_float4(0.f, 0.f, 0.f, 0.f);
            int t = t0 + lr;
            if (t < Tc) yv = *(const float4*)(Y + (size_t)(b * Tc + t) * Nn + k0 + lc);
            __syncthreads();
            Ws[lc + 0][lr] = wv.x; Ws[lc + 1][lr] = wv.y;
            Ws[lc + 2][lr] = wv.z; Ws[lc + 3][lr] = wv.w;
            Ys[lc + 0][lr] = yv.x; Ys[lc + 1][lr] = yv.y;
            Ys[lc + 2][lr] = yv.z; Ys[lc + 3][lr] = yv.w;
            __syncthreads();
#pragma unroll
            for (int kk = 0; kk < 16; kk++) {
                float4 av = *(const float4*)&Ws[kk][ty << 2];
                float4 bv = *(const float4*)&Ys[kk][tx << 2];
                acc[0][0] += av.x * bv.x; acc[0][1] += av.x * bv.y;
                acc[0][2] += av.x * bv.z; acc[0][3] += av.x * bv.w;
                acc[1][0] += av.y * bv.x; acc[1][1] += av.y * bv.y;
                acc[1][2] += av.y * bv.z; acc[1][3] += av.y * bv.w;
                acc[2][0] += av.z * bv.x; acc[2][1] += av.z * bv.y;
                acc[2][2] += av.z * bv.z; acc[2][3] += av.z * bv.w;
                acc[3][0] += av.w * bv.x; acc[3][1] += av.w * bv.y;
                acc[3][2] += av.w * bv.z; acc[3][3] += av.w * bv.w;
            }
        }
        // gelu + accumulate valid t
#pragma unroll
        for (int i = 0; i < 4; i++) {
            float bias = pwb[o0 + (ty << 2) + i];
#pragma unroll
            for (int j = 0; j < 4; j++) {
                int t = t0 + (tx << 2) + j;
                if (t < Tc) tsum[i] += gelu_exact(acc[i][j] + bias);
            }
        }
    }
    __syncthreads();
#pragma unroll
    for (int i = 0; i < 4; i++) red[(ty << 2) + i][tx] = tsum[i];
    __syncthreads();
    if (tid < 64) {
        float s = 0.f;
#pragma unroll
        for (int j = 0; j < 16; j++) s += red[tid][j];
        qmean[(size_t)b * OD + o0 + tid] = s * (1.0f / 289.0f);
    }
}

// ---------------------------------------------------------------------------
// Stage 3: LayerNorm over D=32, one thread per (b,n) row. Writes q output.
// ---------------------------------------------------------------------------
__global__ __launch_bounds__(256) void ln_kernel(
    const float* __restrict__ qmean, const float* __restrict__ g,
    const float* __restrict__ beta, float* __restrict__ qout)
{
    int r = blockIdx.x * 256 + threadIdx.x;
    if (r >= Bb * Nn) return;
    const float4* p = (const float4*)(qmean + (size_t)r * Dd);
    float v[32];
#pragma unroll
    for (int i = 0; i < 8; i++) {
        float4 t = p[i];
        v[i * 4 + 0] = t.x; v[i * 4 + 1] = t.y; v[i * 4 + 2] = t.z; v[i * 4 + 3] = t.w;
    }
    float mu = 0.f;
#pragma unroll
    for (int d = 0; d < 32; d++) mu += v[d];
    mu *= (1.0f / 32.0f);
    float var = 0.f;
#pragma unroll
    for (int d = 0; d < 32; d++) { float c = v[d] - mu; var += c * c; }
    var *= (1.0f / 32.0f);
    float inv = rsqrtf(var + 1e-5f);
    float* op = qout + (size_t)r * Dd;
#pragma unroll
    for (int d = 0; d < 32; d++) op[d] = (v[d] - mu) * inv * g[d] + beta[d];
}

// ---------------------------------------------------------------------------
// Stage 4a: per-batch L2 norm of q (flattened 32768)
// ---------------------------------------------------------------------------
__global__ __launch_bounds__(256) void qnorm_kernel(
    const float* __restrict__ qout, float* __restrict__ qnorm)
{
    int b = blockIdx.x, tid = threadIdx.x;
    float s = 0.f;
    for (int e = tid; e < OD; e += 256) { float v = qout[(size_t)b * OD + e]; s += v * v; }
    __shared__ float red[256];
    red[tid] = s; __syncthreads();
    for (int st = 128; st > 0; st >>= 1) {
        if (tid < st) red[tid] += red[tid + st];
        __syncthreads();
    }
    if (tid == 0) qnorm[b] = fmaxf(sqrtf(red[0]), 1e-12f);
}

// ---------------------------------------------------------------------------
// Stage 4b: sim[b][m] = masked/diversity-scaled cosine sim. Block per m.
// ---------------------------------------------------------------------------
__global__ __launch_bounds__(256) void sim_kernel(
    const float* __restrict__ mem, const float* __restrict__ qout,
    const float* __restrict__ qnorm, const float* __restrict__ year_q,
    const float* __restrict__ mem_years, const int* __restrict__ season_q,
    const int* __restrict__ mem_seasons, float* __restrict__ sim)
{
    int m = blockIdx.x;
    const float* mp = mem + (size_t)m * OD;
    float dot[16];
#pragma unroll
    for (int j = 0; j < 16; j++) dot[j] = 0.f;
    float n2 = 0.f;
    for (int e = threadIdx.x; e < OD; e += 256) {
        float mv = mp[e];
        n2 += mv * mv;
#pragma unroll
        for (int j = 0; j < 16; j++) dot[j] += mv * qout[(size_t)j * OD + e];
    }
    __shared__ float r2[17][4];
    int lane = threadIdx.x & 63, wid = threadIdx.x >> 6;
#pragma unroll
    for (int j = 0; j < 16; j++) {
        float v = dot[j];
        for (int o = 32; o > 0; o >>= 1) v += __shfl_xor(v, o);
        if (lane == 0) r2[j][wid] = v;
    }
    {
        float v = n2;
        for (int o = 32; o > 0; o >>= 1) v += __shfl_xor(v, o);
        if (lane == 0) r2[16][wid] = v;
    }
    __syncthreads();
    if (threadIdx.x < 16) {
        int b = threadIdx.x;
        float d  = r2[b][0] + r2[b][1] + r2[b][2] + r2[b][3];
        float nn = r2[16][0] + r2[16][1] + r2[16][2] + r2[16][3];
        float mn = fmaxf(sqrtf(nn), 1e-12f);
        float c  = d / (qnorm[b] * mn);
        float s  = (season_q[b] == mem_seasons[m]) ? c : NEGV;
        float dy = fabsf(year_q[b] - mem_years[m]);
        s *= 1.0f - 0.5f * expf(-0.5f * dy);   // 0.5 + 0.5*(1 - exp(-dy/2))
        sim[b * Mm + m] = s;
    }
}

// ---------------------------------------------------------------------------
// Stage 4c: top-8 per batch (iterative argmax, lowest-index tie-break)
// ---------------------------------------------------------------------------
__global__ __launch_bounds__(256) void topk_kernel(
    const float* __restrict__ sim, int* __restrict__ idxb)
{
    int b = blockIdx.x, tid = threadIdx.x;
    __shared__ float vals[Mm];
    __shared__ float bv[256];
    __shared__ int   bi[256];
    for (int e = tid; e < Mm; e += 256) vals[e] = sim[b * Mm + e];
    for (int k = 0; k < Kk; k++) {
        __syncthreads();
        float best = -3.4e38f; int besti = Mm;
        for (int e = tid; e < Mm; e += 256) {
            float v = vals[e];
            if (v > best || (v == best && e < besti)) { best = v; besti = e; }
        }
        bv[tid] = best; bi[tid] = besti;
        __syncthreads();
        for (int st = 128; st > 0; st >>= 1) {
            if (tid < st) {
                if (bv[tid + st] > bv[tid] ||
                    (bv[tid + st] == bv[tid] && bi[tid + st] < bi[tid])) {
                    bv[tid] = bv[tid + st]; bi[tid] = bi[tid + st];
                }
            }
            __syncthreads();
        }
        if (tid == 0) { idxb[b * Kk + k] = bi[0]; vals[bi[0]] = -3.4e38f; }
    }
}

// ---------------------------------------------------------------------------
// Stage 5: fused cross-attention + out_proj + final proj. Block per (b,n), 64 thr.
// ---------------------------------------------------------------------------
__global__ __launch_bounds__(64) void attn_kernel(
    const float* __restrict__ qout, const float* __restrict__ mem,
    const int* __restrict__ idxb,
    const float* __restrict__ inw, const float* __restrict__ inb,
    const float* __restrict__ ow, const float* __restrict__ ob,
    const float* __restrict__ pw, const float* __restrict__ pb,
    float* __restrict__ out)
{
    int bn = blockIdx.x;
    int b = bn >> 10, n = bn & 1023;
    int tid = threadIdx.x;
    __shared__ float qrow[32], qp[32];
    __shared__ float kv[8][32];
    __shared__ float kp[8][32], vp[8][32];
    __shared__ float sc[4][8], attw[4][8];
    __shared__ float ao[32], o1[32];

    for (int i = tid; i < 256; i += 64) {
        int k = i >> 5, d = i & 31;
        kv[k][d] = mem[((size_t)idxb[b * Kk + k] * Nn + n) * Dd + d];
    }
    if (tid < 32) qrow[tid] = qout[(size_t)bn * Dd + tid];
    __syncthreads();
    if (tid < 32) {
        float s = inb[tid];
#pragma unroll
        for (int d = 0; d < 32; d++) s += inw[tid * 32 + d] * qrow[d];
        qp[tid] = s;
    }
    for (int i = tid; i < 256; i += 64) {
        int k = i >> 5, o = i & 31;
        float sk = inb[32 + o], sv = inb[64 + o];
#pragma unroll
        for (int d = 0; d < 32; d++) {
            float kvv = kv[k][d];
            sk += inw[(32 + o) * 32 + d] * kvv;
            sv += inw[(64 + o) * 32 + d] * kvv;
        }
        kp[k][o] = sk; vp[k][o] = sv;
    }
    __syncthreads();
    if (tid < 32) {
        int h = tid >> 3, k = tid & 7;
        float s = 0.f;
#pragma unroll
        for (int d = 0; d < 8; d++) s += qp[h * 8 + d] * kp[k][h * 8 + d];
        sc[h][k] = s * 0.35355339059327373f;   // 1/sqrt(8)
    }
    __syncthreads();
    if (tid < 4) {
        int h = tid;
        float mx = sc[h][0];
#pragma unroll
        for (int k = 1; k < 8; k++) mx = fmaxf(mx, sc[h][k]);
        float e[8], sum = 0.f;
#pragma unroll
        for (int k = 0; k < 8; k++) { e[k] = expf(sc[h][k] - mx); sum += e[k]; }
#pragma unroll
        for (int k = 0; k < 8; k++) attw[h][k] = e[k] / sum;
    }
    __syncthreads();
    if (tid < 32) {
        int h = tid >> 3;
        float s = 0.f;
#pragma unroll
        for (int k = 0; k < 8; k++) s += attw[h][k] * vp[k][tid];
        ao[tid] = s;
    }
    __syncthreads();
    if (tid < 32) {
        float s = ob[tid];
#pragma unroll
        for (int i = 0; i < 32; i++) s += ow[tid * 32 + i] * ao[i];
        o1[tid] = s;
    }
    __syncthreads();
    if (tid < 32) {
        float s = pb[tid];
#pragma unroll
        for (int i = 0; i < 32; i++) s += pw[tid * 32 + i] * o1[i];
        out[(size_t)bn * Dd + tid] = s;
    }
}

// ---------------------------------------------------------------------------
extern "C" void kernel_launch(void* const* d_in, const int* in_sizes, int n_in,
                              void* d_out, int out_size, void* d_ws, size_t ws_size,
                              hipStream_t stream)
{
    const float* x          = (const float*)d_in[0];
    const float* year_q     = (const float*)d_in[1];
    const float* dw_w       = (const float*)d_in[2];
    const float* dw_b       = (const float*)d_in[3];
    const float* pw_w       = (const float*)d_in[4];
    const float* pw_b       = (const float*)d_in[5];
    const float* ln_g       = (const float*)d_in[6];
    const float* ln_b       = (const float*)d_in[7];
    const float* mem        = (const float*)d_in[8];
    const float* mem_years  = (const float*)d_in[9];
    const float* in_w       = (const float*)d_in[10];
    const float* in_b       = (const float*)d_in[11];
    const float* out_w      = (const float*)d_in[12];
    const float* out_b      = (const float*)d_in[13];
    const float* proj_w     = (const float*)d_in[14];
    const float* proj_b     = (const float*)d_in[15];
    const int*   season_q   = (const int*)d_in[16];
    const int*   mem_seas   = (const int*)d_in[17];

    float* out  = (float*)d_out;            // [B*N*D] final out
    float* qout = out + (size_t)Bb * Nn * Dd; // [B*N*D] q output (second tuple elem)

    float* ws    = (float*)d_ws;
    float* Y     = ws;                       // 4624*1024 = 4,734,976
    float* qmean = Y + (size_t)Bb * Tc * Nn; // 524,288
    float* qnorm = qmean + (size_t)Bb * OD;  // 16
    float* sim   = qnorm + 16;               // 65,536
    int*   idxb  = (int*)(sim + Bb * Mm);    // 128

    dwconv_kernel<<<(Bb * Tc * Nn + 255) / 256, 256, 0, stream>>>(x, dw_w, dw_b, Y);
    encode_gemm<<<dim3(OD / 64, Bb), 256, 0, stream>>>(Y, pw_w, pw_b, qmean);
    ln_kernel<<<(Bb * Nn + 255) / 256, 256, 0, stream>>>(qmean, ln_g, ln_b, qout);
    qnorm_kernel<<<Bb, 256, 0, stream>>>(qout, qnorm);
    sim_kernel<<<Mm, 256, 0, stream>>>(mem, qout, qnorm, year_q, mem_years,
                                       season_q, mem_seas, sim);
    topk_kernel<<<Bb, 256, 0, stream>>>(sim, idxb);
    attn_kernel<<<Bb * Nn, 64, 0, stream>>>(qout, mem, idxb, in_w, in_b,
                                            out_w, out_b, proj_w, proj_b, out);
}

// Round 2
// 1818.190 us; speedup vs baseline: 3.5760x; 3.5760x over previous
//
#include <hip/hip_runtime.h>
#include <math.h>

// Shapes
#define Bb 16
#define Tt 288
#define Tc 289          // conv output length: 288 + 6 + 6 - 12 + 1
#define Nn 1024
#define Dd 32
#define Mm 4096
#define Kk 8
#define OD 32768        // N*D  (GEMM M)
#define BT 4624         // B*Tc (GEMM N, valid)
#define BTP 4736        // padded to 37*128
#define NEGV (-10000.0f)

typedef __bf16 bfrag8 __attribute__((ext_vector_type(8)));
typedef float floatx4 __attribute__((ext_vector_type(4)));

__device__ __forceinline__ float gelu_exact(float x) {
    return 0.5f * x * (1.0f + erff(x * 0.7071067811865476f));
}

// fp32 -> bf16 bits, round-to-nearest-even (finite inputs)
__device__ __forceinline__ ushort f2b(float f) {
    unsigned int x = __float_as_uint(f);
    return (ushort)((x + 0x7fffu + ((x >> 16) & 1u)) >> 16);
}

__device__ __forceinline__ void gl2lds16(const void* g, void* l) {
    __builtin_amdgcn_global_load_lds(
        (const __attribute__((address_space(1))) unsigned int*)g,
        (__attribute__((address_space(3))) unsigned int*)l, 16, 0, 0);
}

// ---------------------------------------------------------------------------
// W fp32 [32768][1024] -> bf16. 8 elements / thread.
// ---------------------------------------------------------------------------
__global__ __launch_bounds__(256) void wcvt_kernel(
    const float* __restrict__ W, ushort* __restrict__ Wb)
{
    size_t base = ((size_t)blockIdx.x * 256 + threadIdx.x) * 8;
    if (base >= (size_t)OD * Nn) return;
    float4 f0 = *(const float4*)(W + base);
    float4 f1 = *(const float4*)(W + base + 4);
    union { ushort u[8]; uint4 v; } p;
    p.u[0] = f2b(f0.x); p.u[1] = f2b(f0.y); p.u[2] = f2b(f0.z); p.u[3] = f2b(f0.w);
    p.u[4] = f2b(f1.x); p.u[5] = f2b(f1.y); p.u[6] = f2b(f1.z); p.u[7] = f2b(f1.w);
    *(uint4*)(Wb + base) = p.v;
}

// ---------------------------------------------------------------------------
// Stage 1: depthwise conv (k=12, pad 6/6) + bias + GELU -> bf16 Y[4736][1024]
// rows >= 4624 are zero padding for the GEMM N dimension.
// ---------------------------------------------------------------------------
__global__ __launch_bounds__(256) void dwconv_kernel(
    const float* __restrict__ x, const float* __restrict__ w,
    const float* __restrict__ bias, ushort* __restrict__ Y)
{
    int tid = blockIdx.x * 256 + threadIdx.x;
    if (tid >= BTP * Nn) return;
    int n  = tid & (Nn - 1);
    int bt = tid >> 10;
    if (bt >= BT) { Y[tid] = 0; return; }
    int b  = bt / Tc;
    int t  = bt - b * Tc;
    const float* xp = x + (size_t)b * Tt * Nn + n;
    const float* wp = w + n * 12;
    float acc = 0.f;
#pragma unroll
    for (int k = 0; k < 12; k++) {
        int ti = t - 6 + k;
        if (ti >= 0 && ti < Tt) acc += xp[(size_t)ti * Nn] * wp[k];
    }
    acc += bias[n];
    Y[tid] = f2b(gelu_exact(acc));
}

__global__ __launch_bounds__(256) void zeroq_kernel(float* __restrict__ q)
{
    int tid = blockIdx.x * 256 + threadIdx.x;
    if (tid < Bb * OD) q[tid] = 0.f;
}

// ---------------------------------------------------------------------------
// Stage 2: bf16 MFMA GEMM  C[o][bt] = sum_c W[o][c]*Y[bt][c], fused
// bias+GELU+mean-over-t epilogue -> qsum[b][o] (atomic partial sums).
// 128x128 tile, BK=32, 16x16x32 MFMA, global_load_lds width 16.
// ---------------------------------------------------------------------------
__global__ __launch_bounds__(256) void encode_gemm(
    const ushort* __restrict__ Wb, const ushort* __restrict__ Y,
    const float* __restrict__ pwb, float* __restrict__ qsum)
{
    __shared__ __align__(16) ushort As[128 * 32];
    __shared__ __align__(16) ushort Bs[128 * 32];
    __shared__ float biasS[128];

    int tid  = threadIdx.x;
    int lane = tid & 63, w = tid >> 6;
    int o0 = blockIdx.x * 128;
    int n0 = blockIdx.y * 128;

    if (tid < 128) biasS[tid] = pwb[o0 + tid];

    int rowbase = w * 32 + (lane >> 2);
    int kc = (lane & 3) * 8;
    const ushort* Ag = Wb + (size_t)(o0 + rowbase) * Nn + kc;
    const ushort* Bg = Y  + (size_t)(n0 + rowbase) * Nn + kc;
    char* Al = (char*)As + w * 2048;   // wave-uniform; HW adds lane*16
    char* Bl = (char*)Bs + w * 2048;

    int wm = w >> 1, wn = w & 1;
    int c = lane & 15, g = lane >> 4;
    const ushort* Ard = As + (wm * 64 + c) * 32 + g * 8;
    const ushort* Brd = Bs + (wn * 64 + c) * 32 + g * 8;

    floatx4 acc[4][4];
#pragma unroll
    for (int i = 0; i < 4; i++)
#pragma unroll
        for (int j = 0; j < 4; j++) acc[i][j] = (floatx4){0.f, 0.f, 0.f, 0.f};

    for (int k0 = 0; k0 < Nn; k0 += 32) {
        __syncthreads();
        gl2lds16(Ag + k0,           Al);
        gl2lds16(Ag + k0 + 16 * Nn, Al + 1024);
        gl2lds16(Bg + k0,           Bl);
        gl2lds16(Bg + k0 + 16 * Nn, Bl + 1024);
        __syncthreads();
        bfrag8 a[4], bq[4];
#pragma unroll
        for (int i = 0; i < 4; i++) a[i]  = *(const bfrag8*)(Ard + i * 16 * 32);
#pragma unroll
        for (int j = 0; j < 4; j++) bq[j] = *(const bfrag8*)(Brd + j * 16 * 32);
#pragma unroll
        for (int i = 0; i < 4; i++)
#pragma unroll
            for (int j = 0; j < 4; j++)
                acc[i][j] = __builtin_amdgcn_mfma_f32_16x16x32_bf16(
                    a[i], bq[j], acc[i][j], 0, 0, 0);
    }

    // Epilogue: gelu(acc+bias), reduce over this block's bt columns per batch
    // segment (<=2 per 128-col tile), atomicAdd into qsum[b][o].
    int b0 = n0 / Tc;
    int bsplit = (b0 + 1) * Tc;
    bool hasb1 = (bsplit < n0 + 128) && (bsplit < BT);
#pragma unroll
    for (int i = 0; i < 4; i++) {
        int m = wm * 64 + i * 16 + g * 4;
#pragma unroll
        for (int r = 0; r < 4; r++) {
            float bias = biasS[m + r];
            float s0 = 0.f, s1 = 0.f;
#pragma unroll
            for (int j = 0; j < 4; j++) {
                int bt = n0 + wn * 64 + j * 16 + c;
                if (bt < BT) {
                    float v = gelu_exact(acc[i][j][r] + bias);
                    if (bt < bsplit) s0 += v; else s1 += v;
                }
            }
#pragma unroll
            for (int off = 1; off < 16; off <<= 1) {
                s0 += __shfl_xor(s0, off);
                s1 += __shfl_xor(s1, off);
            }
            if (c == 0) {
                int o = o0 + m + r;
                atomicAdd(&qsum[(size_t)b0 * OD + o], s0);
                if (hasb1) atomicAdd(&qsum[(size_t)(b0 + 1) * OD + o], s1);
            }
        }
    }
}

// ---------------------------------------------------------------------------
// Stage 3: LayerNorm over D=32 (folds the 1/289 mean scale)
// ---------------------------------------------------------------------------
__global__ __launch_bounds__(256) void ln_kernel(
    const float* __restrict__ qsum, const float* __restrict__ g,
    const float* __restrict__ beta, float* __restrict__ qout)
{
    int r = blockIdx.x * 256 + threadIdx.x;
    if (r >= Bb * Nn) return;
    const float4* p = (const float4*)(qsum + (size_t)r * Dd);
    float v[32];
#pragma unroll
    for (int i = 0; i < 8; i++) {
        float4 t = p[i];
        v[i * 4 + 0] = t.x * (1.0f / 289.0f); v[i * 4 + 1] = t.y * (1.0f / 289.0f);
        v[i * 4 + 2] = t.z * (1.0f / 289.0f); v[i * 4 + 3] = t.w * (1.0f / 289.0f);
    }
    float mu = 0.f;
#pragma unroll
    for (int d = 0; d < 32; d++) mu += v[d];
    mu *= (1.0f / 32.0f);
    float var = 0.f;
#pragma unroll
    for (int d = 0; d < 32; d++) { float cc = v[d] - mu; var += cc * cc; }
    var *= (1.0f / 32.0f);
    float inv = rsqrtf(var + 1e-5f);
    float* op = qout + (size_t)r * Dd;
#pragma unroll
    for (int d = 0; d < 32; d++) op[d] = (v[d] - mu) * inv * g[d] + beta[d];
}

// ---------------------------------------------------------------------------
// Stage 4a: per-batch L2 norm of q (flattened 32768)
// ---------------------------------------------------------------------------
__global__ __launch_bounds__(256) void qnorm_kernel(
    const float* __restrict__ qout, float* __restrict__ qnorm)
{
    int b = blockIdx.x, tid = threadIdx.x;
    float s = 0.f;
    for (int e = tid; e < OD; e += 256) { float v = qout[(size_t)b * OD + e]; s += v * v; }
    __shared__ float red[256];
    red[tid] = s; __syncthreads();
    for (int st = 128; st > 0; st >>= 1) {
        if (tid < st) red[tid] += red[tid + st];
        __syncthreads();
    }
    if (tid == 0) qnorm[b] = fmaxf(sqrtf(red[0]), 1e-12f);
}

// ---------------------------------------------------------------------------
// Stage 4b: sim[b][m] = masked/diversity-scaled cosine sim. Block per m.
// ---------------------------------------------------------------------------
__global__ __launch_bounds__(256) void sim_kernel(
    const float* __restrict__ mem, const float* __restrict__ qout,
    const float* __restrict__ qnorm, const float* __restrict__ year_q,
    const float* __restrict__ mem_years, const int* __restrict__ season_q,
    const int* __restrict__ mem_seasons, float* __restrict__ sim)
{
    int m = blockIdx.x;
    const float* mp = mem + (size_t)m * OD;
    float dot[16];
#pragma unroll
    for (int j = 0; j < 16; j++) dot[j] = 0.f;
    float n2 = 0.f;
    for (int e = threadIdx.x; e < OD; e += 256) {
        float mv = mp[e];
        n2 += mv * mv;
#pragma unroll
        for (int j = 0; j < 16; j++) dot[j] += mv * qout[(size_t)j * OD + e];
    }
    __shared__ float r2[17][4];
    int lane = threadIdx.x & 63, wid = threadIdx.x >> 6;
#pragma unroll
    for (int j = 0; j < 16; j++) {
        float v = dot[j];
        for (int o = 32; o > 0; o >>= 1) v += __shfl_xor(v, o);
        if (lane == 0) r2[j][wid] = v;
    }
    {
        float v = n2;
        for (int o = 32; o > 0; o >>= 1) v += __shfl_xor(v, o);
        if (lane == 0) r2[16][wid] = v;
    }
    __syncthreads();
    if (threadIdx.x < 16) {
        int b = threadIdx.x;
        float d  = r2[b][0] + r2[b][1] + r2[b][2] + r2[b][3];
        float nn = r2[16][0] + r2[16][1] + r2[16][2] + r2[16][3];
        float mn = fmaxf(sqrtf(nn), 1e-12f);
        float cc = d / (qnorm[b] * mn);
        float s  = (season_q[b] == mem_seasons[m]) ? cc : NEGV;
        float dy = fabsf(year_q[b] - mem_years[m]);
        s *= 1.0f - 0.5f * expf(-0.5f * dy);   // 0.5 + 0.5*(1 - exp(-dy/2))
        sim[b * Mm + m] = s;
    }
}

// ---------------------------------------------------------------------------
// Stage 4c: top-8 per batch (iterative argmax, lowest-index tie-break)
// ---------------------------------------------------------------------------
__global__ __launch_bounds__(256) void topk_kernel(
    const float* __restrict__ sim, int* __restrict__ idxb)
{
    int b = blockIdx.x, tid = threadIdx.x;
    __shared__ float vals[Mm];
    __shared__ float bv[256];
    __shared__ int   bi[256];
    for (int e = tid; e < Mm; e += 256) vals[e] = sim[b * Mm + e];
    for (int k = 0; k < Kk; k++) {
        __syncthreads();
        float best = -3.4e38f; int besti = Mm;
        for (int e = tid; e < Mm; e += 256) {
            float v = vals[e];
            if (v > best || (v == best && e < besti)) { best = v; besti = e; }
        }
        bv[tid] = best; bi[tid] = besti;
        __syncthreads();
        for (int st = 128; st > 0; st >>= 1) {
            if (tid < st) {
                if (bv[tid + st] > bv[tid] ||
                    (bv[tid + st] == bv[tid] && bi[tid + st] < bi[tid])) {
                    bv[tid] = bv[tid + st]; bi[tid] = bi[tid + st];
                }
            }
            __syncthreads();
        }
        if (tid == 0) { idxb[b * Kk + k] = bi[0]; vals[bi[0]] = -3.4e38f; }
    }
}

// ---------------------------------------------------------------------------
// Stage 5: fused cross-attention + out_proj + final proj. Block per (b,n).
// ---------------------------------------------------------------------------
__global__ __launch_bounds__(64) void attn_kernel(
    const float* __restrict__ qout, const float* __restrict__ mem,
    const int* __restrict__ idxb,
    const float* __restrict__ inw, const float* __restrict__ inb,
    const float* __restrict__ ow, const float* __restrict__ ob,
    const float* __restrict__ pw, const float* __restrict__ pb,
    float* __restrict__ out)
{
    int bn = blockIdx.x;
    int b = bn >> 10, n = bn & 1023;
    int tid = threadIdx.x;
    __shared__ float qrow[32], qp[32];
    __shared__ float kv[8][32];
    __shared__ float kp[8][32], vp[8][32];
    __shared__ float sc[4][8], attw[4][8];
    __shared__ float ao[32], o1[32];

    for (int i = tid; i < 256; i += 64) {
        int k = i >> 5, d = i & 31;
        kv[k][d] = mem[((size_t)idxb[b * Kk + k] * Nn + n) * Dd + d];
    }
    if (tid < 32) qrow[tid] = qout[(size_t)bn * Dd + tid];
    __syncthreads();
    if (tid < 32) {
        float s = inb[tid];
#pragma unroll
        for (int d = 0; d < 32; d++) s += inw[tid * 32 + d] * qrow[d];
        qp[tid] = s;
    }
    for (int i = tid; i < 256; i += 64) {
        int k = i >> 5, o = i & 31;
        float sk = inb[32 + o], sv = inb[64 + o];
#pragma unroll
        for (int d = 0; d < 32; d++) {
            float kvv = kv[k][d];
            sk += inw[(32 + o) * 32 + d] * kvv;
            sv += inw[(64 + o) * 32 + d] * kvv;
        }
        kp[k][o] = sk; vp[k][o] = sv;
    }
    __syncthreads();
    if (tid < 32) {
        int h = tid >> 3, k = tid & 7;
        float s = 0.f;
#pragma unroll
        for (int d = 0; d < 8; d++) s += qp[h * 8 + d] * kp[k][h * 8 + d];
        sc[h][k] = s * 0.35355339059327373f;   // 1/sqrt(8)
    }
    __syncthreads();
    if (tid < 4) {
        int h = tid;
        float mx = sc[h][0];
#pragma unroll
        for (int k = 1; k < 8; k++) mx = fmaxf(mx, sc[h][k]);
        float e[8], sum = 0.f;
#pragma unroll
        for (int k = 0; k < 8; k++) { e[k] = expf(sc[h][k] - mx); sum += e[k]; }
#pragma unroll
        for (int k = 0; k < 8; k++) attw[h][k] = e[k] / sum;
    }
    __syncthreads();
    if (tid < 32) {
        int h = tid >> 3;
        float s = 0.f;
#pragma unroll
        for (int k = 0; k < 8; k++) s += attw[h][k] * vp[k][tid];
        ao[tid] = s;
    }
    __syncthreads();
    if (tid < 32) {
        float s = ob[tid];
#pragma unroll
        for (int i = 0; i < 32; i++) s += ow[tid * 32 + i] * ao[i];
        o1[tid] = s;
    }
    __syncthreads();
    if (tid < 32) {
        float s = pb[tid];
#pragma unroll
        for (int i = 0; i < 32; i++) s += pw[tid * 32 + i] * o1[i];
        out[(size_t)bn * Dd + tid] = s;
    }
}

// ---------------------------------------------------------------------------
extern "C" void kernel_launch(void* const* d_in, const int* in_sizes, int n_in,
                              void* d_out, int out_size, void* d_ws, size_t ws_size,
                              hipStream_t stream)
{
    const float* x          = (const float*)d_in[0];
    const float* year_q     = (const float*)d_in[1];
    const float* dw_w       = (const float*)d_in[2];
    const float* dw_b       = (const float*)d_in[3];
    const float* pw_w       = (const float*)d_in[4];
    const float* pw_b       = (const float*)d_in[5];
    const float* ln_g       = (const float*)d_in[6];
    const float* ln_b       = (const float*)d_in[7];
    const float* mem        = (const float*)d_in[8];
    const float* mem_years  = (const float*)d_in[9];
    const float* in_w       = (const float*)d_in[10];
    const float* in_b       = (const float*)d_in[11];
    const float* out_w      = (const float*)d_in[12];
    const float* out_b      = (const float*)d_in[13];
    const float* proj_w     = (const float*)d_in[14];
    const float* proj_b     = (const float*)d_in[15];
    const int*   season_q   = (const int*)d_in[16];
    const int*   mem_seas   = (const int*)d_in[17];

    float* out  = (float*)d_out;               // [B*N*D] final out
    float* qout = out + (size_t)Bb * Nn * Dd;  // [B*N*D] q (tuple elem 2)

    char* wsb = (char*)d_ws;
    ushort* Wb    = (ushort*)wsb;                        // 67,108,864 B
    ushort* Y     = (ushort*)(wsb + 67108864);           //  9,699,328 B
    float*  qsum  = (float*)(wsb + 76808192);            //  2,097,152 B
    float*  qnorm = (float*)(wsb + 78905344);            //         64 B
    float*  sim   = (float*)(wsb + 78905600);            //    262,144 B
    int*    idxb  = (int*)(wsb + 79167744);              //        512 B

    wcvt_kernel<<<(OD * Nn / 8 + 255) / 256, 256, 0, stream>>>(pw_w, Wb);
    dwconv_kernel<<<(BTP * Nn + 255) / 256, 256, 0, stream>>>(x, dw_w, dw_b, Y);
    zeroq_kernel<<<(Bb * OD + 255) / 256, 256, 0, stream>>>(qsum);
    encode_gemm<<<dim3(OD / 128, BTP / 128), 256, 0, stream>>>(Wb, Y, pw_b, qsum);
    ln_kernel<<<(Bb * Nn + 255) / 256, 256, 0, stream>>>(qsum, ln_g, ln_b, qout);
    qnorm_kernel<<<Bb, 256, 0, stream>>>(qout, qnorm);
    sim_kernel<<<Mm, 256, 0, stream>>>(mem, qout, qnorm, year_q, mem_years,
                                       season_q, mem_seas, sim);
    topk_kernel<<<Bb, 256, 0, stream>>>(sim, idxb);
    attn_kernel<<<Bb * Nn, 64, 0, stream>>>(qout, mem, idxb, in_w, in_b,
                                            out_w, out_b, proj_w, proj_b, out);
}